// Round 1
// baseline (402.380 us; speedup 1.0000x reference)
//
#include <hip/hip_runtime.h>
#include <hip/hip_fp16.h>

#define B_ 64
#define L_ 512
#define T_ 128
#define NTHR 256

typedef _Float16 h2 __attribute__((ext_vector_type(2)));
typedef unsigned int u32x4 __attribute__((ext_vector_type(4)));

__device__ __forceinline__ float dot2_acc(unsigned int e, unsigned int a, float c) {
#if __has_builtin(__builtin_amdgcn_fdot2)
    h2 ev = __builtin_bit_cast(h2, e);
    h2 av = __builtin_bit_cast(h2, a);
    return __builtin_amdgcn_fdot2(ev, av, c, false);
#else
    __half2 eh = __builtin_bit_cast(__half2, e);
    __half2 ah = __builtin_bit_cast(__half2, a);
    float2 ef = __half22float2(eh), af = __half22float2(ah);
    return c + ef.x * af.x + ef.y * af.y;
#endif
}

__global__ __launch_bounds__(NTHR) void crf_nll_kernel(
        const float* __restrict__ feats,   // [B, L, T]
        const float* __restrict__ trans,   // [T, T]
        const int*   __restrict__ tags,    // [B, L]
        const int*   __restrict__ mask,    // [B, L]
        float*       __restrict__ out)     // [B]
{
    // E = exp(trans) packed as f16x2 over i-pairs: EP[ip][j] = (E[2ip][j], E[2ip+1][j])
    __shared__ __align__(16) unsigned int EP[(T_ / 2) * T_];   // 32 KB
    __shared__ __align__(16) unsigned int apk[T_ / 2];         // aexp packed f16x2
    __shared__ float partial[2][T_];
    __shared__ float red[8];

    const int tid  = threadIdx.x;
    const int b    = blockIdx.x;
    const int lane = tid & 63;
    const int wid  = tid >> 6;
    const int g    = tid >> 7;    // i-split group: 0 -> i in [0,64), 1 -> i in [64,128)
    const int j    = tid & 127;

    // ---- build EP = exp(trans) in f16 ----
    for (int idx = tid; idx < T_ * T_; idx += NTHR) {
        int i  = idx >> 7;
        int jj = idx & 127;
        float e = __expf(trans[idx]);
        ((__half*)EP)[((i >> 1) * T_ + jj) * 2 + (i & 1)] = __float2half(e);
    }

    const float* featb = feats + (size_t)b * L_ * T_;
    const int*   maskb = mask + b * L_;
    const int*   tagb  = tags + b * L_;

    // ---- initial alpha = feats[b, 0, :] ----
    float av = 0.f;
    if (tid < T_) av = featb[tid];

    // initial max over alpha
    if (tid < T_) {
        float v = av;
        #pragma unroll
        for (int off = 32; off >= 1; off >>= 1) v = fmaxf(v, __shfl_xor(v, off));
        if (lane == 0) red[wid] = v;
    }
    __syncthreads();
    float m = fmaxf(red[0], red[1]);

    // ---- forward scan ----
    for (int t = 1; t < L_; ++t) {
        // (A) aexp[i] = exp(alpha[i] - m), stored as f16
        if (tid < T_) {
            ((__half*)apk)[tid] = __float2half(__expf(av - m));
        }
        __syncthreads();

        // (B) partial[g][j] = sum over this group's i-half of aexp[i] * E[i][j]
        float emit = 0.f;
        int   mk   = 1;
        if (tid < T_) {            // prefetch emit/mask early; used in (C)
            emit = featb[t * T_ + tid];
            mk   = maskb[t];
        }
        {
            float s0 = 0.f, s1 = 0.f, s2 = 0.f, s3 = 0.f;
            const unsigned int* ep = EP + g * 32 * T_ + j;   // EP[ip][j], ip local 0..31
            const u32x4* ap = (const u32x4*)(apk + g * 32);
            #pragma unroll
            for (int k = 0; k < 8; ++k) {
                u32x4 a4 = ap[k];                            // broadcast read
                s0 = dot2_acc(ep[(k * 4 + 0) * T_], a4.x, s0);
                s1 = dot2_acc(ep[(k * 4 + 1) * T_], a4.y, s1);
                s2 = dot2_acc(ep[(k * 4 + 2) * T_], a4.z, s2);
                s3 = dot2_acc(ep[(k * 4 + 3) * T_], a4.w, s3);
            }
            partial[g][j] = (s0 + s1) + (s2 + s3);
        }
        __syncthreads();

        // (C) combine, log, add emit; masked update; wave-max for next step
        if (tid < T_) {
            float s  = partial[0][tid] + partial[1][tid];
            float na = __logf(s) + m + emit;
            if (mk) av = na;
            float v = av;
            #pragma unroll
            for (int off = 32; off >= 1; off >>= 1) v = fmaxf(v, __shfl_xor(v, off));
            if (lane == 0) red[wid] = v;
        }
        __syncthreads();

        // (D) new max
        m = fmaxf(red[0], red[1]);
    }

    // ---- norm_score = logsumexp(final alpha) ----
    float e = (tid < T_) ? __expf(av - m) : 0.f;
    if (tid < T_) {
        #pragma unroll
        for (int off = 32; off >= 1; off >>= 1) e += __shfl_xor(e, off);
        if (lane == 0) red[2 + wid] = e;
    }
    __syncthreads();
    float norm = m + __logf(red[2] + red[3]);

    // ---- gold path score ----
    float gacc = 0.f;
    for (int t = tid; t < L_; t += NTHR) {
        int tg = tagb[t];
        gacc += featb[t * T_ + tg] * (float)maskb[t];
        if (t + 1 < L_) {
            gacc += trans[tg * T_ + tagb[t + 1]] * (float)maskb[t + 1];
        }
    }
    #pragma unroll
    for (int off = 32; off >= 1; off >>= 1) gacc += __shfl_xor(gacc, off);
    if (lane == 0) red[4 + wid] = gacc;
    __syncthreads();

    if (tid == 0) {
        out[b] = norm - (red[4] + red[5] + red[6] + red[7]);
    }
}

extern "C" void kernel_launch(void* const* d_in, const int* in_sizes, int n_in,
                              void* d_out, int out_size, void* d_ws, size_t ws_size,
                              hipStream_t stream) {
    const float* feats = (const float*)d_in[0];
    const float* trans = (const float*)d_in[1];
    const int*   tags  = (const int*)d_in[2];
    const int*   mask  = (const int*)d_in[3];
    float* out = (float*)d_out;

    crf_nll_kernel<<<B_, NTHR, 0, stream>>>(feats, trans, tags, mask, out);
}

// Round 2
// 282.146 us; speedup vs baseline: 1.4261x; 1.4261x over previous
//
#include <hip/hip_runtime.h>
#include <hip/hip_fp16.h>

#define B_ 64
#define L_ 512
#define T_ 128
#define NTHR 192   // waves 0,1 = compute (j = tid), wave 2 = stale-sum reducer

typedef _Float16 h2v __attribute__((ext_vector_type(2)));

__device__ __forceinline__ float dot2_acc(unsigned int e, unsigned int a, float c) {
#if __has_builtin(__builtin_amdgcn_fdot2)
    h2v ev = __builtin_bit_cast(h2v, e);
    h2v av = __builtin_bit_cast(h2v, a);
    return __builtin_amdgcn_fdot2(ev, av, c, false);
#else
    __half2 eh = __builtin_bit_cast(__half2, e);
    __half2 ah = __builtin_bit_cast(__half2, a);
    float2 ef = __half22float2(eh), af = __half22float2(ah);
    return c + ef.x * af.x + ef.y * af.y;
#endif
}

__global__ __launch_bounds__(NTHR) void crf_nll_kernel(
        const float* __restrict__ feats,   // [B, L, T]
        const float* __restrict__ trans,   // [T, T]
        const int*   __restrict__ tags,    // [B, L]
        const int*   __restrict__ mask,    // [B, L]
        float*       __restrict__ out)     // [B]
{
    __shared__ __align__(16) unsigned int apk[2][T_ / 2];  // aexp f16x2, double-buffered
    __shared__ float red[2];                               // stale sums (ping-pong)
    __shared__ float redx[8];

    const int tid  = threadIdx.x;
    const int b    = blockIdx.x;
    const int lane = tid & 63;
    const int wid  = tid >> 6;
    const int j    = tid;               // tag index for compute threads (tid < 128)

    const float* featb = feats + (size_t)b * L_ * T_;
    const int*   maskb = mask + b * L_;
    const int*   tagb  = tags + b * L_;

    // ---- E[*, j] column in registers (f16x2 over i-pairs) ----
    unsigned int ECol[T_ / 2];
    if (tid < T_) {
        #pragma unroll
        for (int ip = 0; ip < T_ / 2; ++ip) {
            float e0 = __expf(trans[(2 * ip) * T_ + j]);
            float e1 = __expf(trans[(2 * ip + 1) * T_ + j]);
            __half2 h = __floats2half2_rn(e0, e1);
            ECol[ip] = __builtin_bit_cast(unsigned int, h);
        }
    }

    // ---- init: alpha_0 = emit_0 ----
    float e0v = 0.f;
    if (tid < T_) {
        e0v = featb[j];
        float v = e0v;
        #pragma unroll
        for (int off = 32; off >= 1; off >>= 1) v = fmaxf(v, __shfl_xor(v, off));
        if (lane == 0) redx[wid] = v;
    }
    __syncthreads();
    const float m0 = fmaxf(redx[0], redx[1]);
    float N = m0;                 // running log-normalizer (uniform on compute threads)
    float xcom = 0.f;             // committed aexp for this j
    if (tid < T_) {
        xcom = __expf(e0v - m0);
        float v = xcom;
        #pragma unroll
        for (int off = 32; off >= 1; off >>= 1) v += __shfl_xor(v, off);
        if (lane == 0) redx[2 + wid] = v;
        ((__half*)apk[0])[j] = __float2half(xcom);
    }
    __syncthreads();
    if (tid == 0) {
        float s0 = redx[2] + redx[3];
        red[0] = s0;
        red[1] = s0;
    }

    // ---- emit/mask prefetch pipeline (depth 2) ----
    // before iter t: exq = exp(emit_t), mkq = mask_t, fb1 = emit_{t+1}, fb2 = emit_{t+2}
    float exq = 0.f, fb1 = 0.f, fb2 = 0.f;
    int mkq = 1, mkb1 = 1, mkb2 = 1;
    if (tid < T_) {
        exq = __expf(featb[1 * T_ + j]);
        fb1 = featb[2 * T_ + j];
        fb2 = featb[3 * T_ + j];
        mkq  = maskb[1];
        mkb1 = maskb[2];
        mkb2 = maskb[3];
    }

    const unsigned int ONE2 = 0x3C003C00u;   // (1.0h, 1.0h)
    int pr = 0;

    // ---- forward scan: ONE barrier per step ----
    for (int t = 1; t < L_; ++t) {
        // prefetch emit/mask for t+3 (clamped)
        const int tn = (t + 3 < L_) ? (t + 3) : (L_ - 1);
        float fn = 0.f; int mn = 1;
        if (tid < T_) {
            fn = featb[tn * T_ + j];
            mn = maskb[tn];
        }

        __syncthreads();                       // apk[pr] + red[t&1] ready
        const float redv = red[t & 1];

        if (tid < T_) {
            const float rcpS = 1.0f / (redv * 128.0f);
            const float logC = __logf(redv) + 4.8520303f;   // ln(redv*128)

            float s0 = 0.f, s1 = 0.f, s2 = 0.f, s3 = 0.f;
            const uint4* ap = (const uint4*)apk[pr];
            #pragma unroll
            for (int k = 0; k < 16; ++k) {
                uint4 a4 = ap[k];              // broadcast ds_read_b128
                s0 = dot2_acc(ECol[4 * k + 0], a4.x, s0);
                s1 = dot2_acc(ECol[4 * k + 1], a4.y, s1);
                s2 = dot2_acc(ECol[4 * k + 2], a4.z, s2);
                s3 = dot2_acc(ECol[4 * k + 3], a4.w, s3);
            }
            const float ssum = (s0 + s1) + (s2 + s3);
            const float x = ssum * exq * rcpS;
            if (mkq) { xcom = x; N += logC; }
            ((__half*)apk[pr ^ 1])[j] = __float2half(xcom);

            // rotate prefetch pipeline
            exq = __expf(fb1);
            mkq = mkb1;
            fb1 = fb2;  mkb1 = mkb2;
            fb2 = fn;   mkb2 = mn;
        } else if (wid == 2) {
            // stale-sum reducer: S = sum of aexp_{t-1}, for use at step t+1
            float ps = dot2_acc(apk[pr][lane], ONE2, 0.f);
            #pragma unroll
            for (int off = 32; off >= 1; off >>= 1) ps += __shfl_xor(ps, off);
            if (lane == 0) red[(t + 1) & 1] = ps;
        }
        pr ^= 1;
    }

    // ---- norm = N + log(sum xcom) ----
    __syncthreads();
    if (tid < T_) {
        float v = xcom;
        #pragma unroll
        for (int off = 32; off >= 1; off >>= 1) v += __shfl_xor(v, off);
        if (lane == 0) redx[wid] = v;
    }
    __syncthreads();
    const float norm = N + __logf(redx[0] + redx[1]);

    // ---- gold path score ----
    float gacc = 0.f;
    for (int t = tid; t < L_; t += NTHR) {
        int tg = tagb[t];
        gacc += featb[t * T_ + tg] * (float)maskb[t];
        if (t + 1 < L_) {
            gacc += trans[tg * T_ + tagb[t + 1]] * (float)maskb[t + 1];
        }
    }
    #pragma unroll
    for (int off = 32; off >= 1; off >>= 1) gacc += __shfl_xor(gacc, off);
    if (lane == 0) redx[4 + wid] = gacc;
    __syncthreads();

    if (tid == 0) {
        out[b] = norm - (redx[4] + redx[5] + redx[6]);
    }
}

extern "C" void kernel_launch(void* const* d_in, const int* in_sizes, int n_in,
                              void* d_out, int out_size, void* d_ws, size_t ws_size,
                              hipStream_t stream) {
    const float* feats = (const float*)d_in[0];
    const float* trans = (const float*)d_in[1];
    const int*   tags  = (const int*)d_in[2];
    const int*   mask  = (const int*)d_in[3];
    float* out = (float*)d_out;

    crf_nll_kernel<<<B_, NTHR, 0, stream>>>(feats, trans, tags, mask, out);
}